// Round 1
// baseline (12512.022 us; speedup 1.0000x reference)
//
#include <hip/hip_runtime.h>

#define THREADS 256
#define T_TOT 432
#define T_IN  144
#define T_OUT 288

// ws layout (floats):
// [0,65536)        h0 buf0      [65536,131072)  h0 buf1     (layout [hidden][batch])
// [131072,196608)  h2 buf0      [196608,262144) h2 buf1
// [262144, +256 u32) barrier counters (16 groups, 64B-padded)

__device__ __forceinline__ float sigf(float x){ return 1.0f/(1.0f + __expf(-x)); }
__device__ __forceinline__ float tanhfast(float x){ return 1.0f - 2.0f/(__expf(2.0f*x)+1.0f); }

extern "C" __global__ void gru_init(float* __restrict__ ws, float* __restrict__ out,
                                    const float* __restrict__ b_proj){
  int i = blockIdx.x*THREADS + threadIdx.x;
  if (i < 262144) ws[i] = 0.0f;
  if (i < 256) ((unsigned*)(ws + 262144))[i] = 0u;
  if (i < 73728) out[i] = b_proj[0];
}

extern "C" __global__ void __launch_bounds__(THREADS, 1) gru_persist(
    const float* __restrict__ x,
    const float* __restrict__ wih0, const float* __restrict__ whh0,
    const float* __restrict__ bih0, const float* __restrict__ bhh0,
    const float* __restrict__ wih1, const float* __restrict__ whh1,
    const float* __restrict__ bih1, const float* __restrict__ bhh1,
    const float* __restrict__ wproj,
    float* __restrict__ out, float* __restrict__ ws)
{
  extern __shared__ float lds[];
  float* Wl = lds;              // 3 mats * [64 k4][48 rows][4 k] = 36864 floats (144 KB)
  float* Hl = lds + 36864;      // [64 k4][16 bi][4 k] = 4096 floats (16 KB)

  const int tid = threadIdx.x;
  const int g   = blockIdx.x & 15;   // hidden slice
  const int bt  = blockIdx.x >> 4;   // batch tile
  const int hi  = tid >> 4;          // hidden unit within slice [0,16)
  const int bi  = tid & 15;          // owned batch col within tile
  const int bg  = bi >> 2;           // batch group for GEMM micro-tile
  const int ks  = bi & 3;            // K-split quarter
  const int rowg = g*16 + hi;        // global hidden index

  float* h0b0 = ws;
  float* h0b1 = ws + 65536;
  float* h2b0 = ws + 131072;
  float* h2b1 = ws + 196608;
  unsigned* mycnt = ((unsigned*)(ws + 262144)) + (bt << 4);

  // ---- one-time: load weight slices into LDS, k4-blocked [k4][row48][4] ----
  {
    const float* srcs[3] = {whh0, wih1, whh1};
    #pragma unroll
    for (int m = 0; m < 3; m++){
      const float* S = srcs[m];
      float* D = Wl + m*12288;
      for (int it = 0; it < 12; it++){
        int d = tid + it*256;          // dest float4-granule: d = k4*48 + row48
        int row48 = d % 48;
        int k4 = d / 48;
        int gate = row48 >> 4;
        int hh = row48 & 15;
        float4 v = *(const float4*)(S + (gate*256 + g*16 + hh)*256 + k4*4);
        *(float4*)(D + d*4) = v;
      }
    }
  }
  // ---- per-thread small weights in registers ----
  float wi0[3][10];
  float bi0g[3], bh0g[3], bi1g[3], bh1g[3];
  #pragma unroll
  for (int G = 0; G < 3; G++){
    #pragma unroll
    for (int d = 0; d < 10; d++) wi0[G][d] = wih0[(G*256 + rowg)*10 + d];
    bi0g[G] = bih0[G*256 + rowg];
    bh0g[G] = bhh0[G*256 + rowg];
    bi1g[G] = bih1[G*256 + rowg];
    bh1g[G] = bhh1[G*256 + rowg];
  }
  const float wp = wproj[rowg];
  __syncthreads();

  // stage a [256 hidden][16 batch] tile from global [h][b] into Hl [k4][bi][4]
  auto STAGE = [&](const float* __restrict__ hg){
    #pragma unroll
    for (int it = 0; it < 4; it++){
      int idx = tid + (it << 8);       // 0..1023
      int k = idx >> 2;
      int q = idx & 3;
      float4 v = *(const float4*)(hg + k*256 + (bt << 4) + (q << 2));
      float* dp = Hl + ((k >> 2) << 6) + (k & 3);
      dp[(q*4 + 0)*4] = v.x;
      dp[(q*4 + 1)*4] = v.y;
      dp[(q*4 + 2)*4] = v.z;
      dp[(q*4 + 3)*4] = v.w;
    }
  };

  auto GEMM3 = [&](int m, float (&aR)[4], float (&aZ)[4], float (&aN)[4]){
    const float4* W4 = ((const float4*)Wl) + m*3072;
    const float4* H4 = (const float4*)Hl;
    #pragma unroll 4
    for (int j = 0; j < 16; j++){
      int k4 = (ks << 4) + j;
      float4 wr = W4[k4*48 + hi];
      float4 wz = W4[k4*48 + 16 + hi];
      float4 wn = W4[k4*48 + 32 + hi];
      #pragma unroll
      for (int bb = 0; bb < 4; bb++){
        float4 hv = H4[(k4 << 4) + (bg << 2) + bb];
        aR[bb] = fmaf(wr.x,hv.x, fmaf(wr.y,hv.y, fmaf(wr.z,hv.z, fmaf(wr.w,hv.w, aR[bb]))));
        aZ[bb] = fmaf(wz.x,hv.x, fmaf(wz.y,hv.y, fmaf(wz.z,hv.z, fmaf(wz.w,hv.w, aZ[bb]))));
        aN[bb] = fmaf(wn.x,hv.x, fmaf(wn.y,hv.y, fmaf(wn.z,hv.z, fmaf(wn.w,hv.w, aN[bb]))));
      }
    }
  };

  auto KRED = [&](float v){
    v += __shfl_xor(v, 1, 64);
    v += __shfl_xor(v, 2, 64);
    return v;
  };
  auto SEL4 = [&](float a0, float a1, float a2, float a3){
    return ks == 0 ? a0 : (ks == 1 ? a1 : (ks == 2 ? a2 : a3));
  };

  int p = 0;
  for (int t = 0; t < T_TOT; t++){
    const float* h0cur = p ? h0b1 : h0b0;
    float*       h0nxt = p ? h0b0 : h0b1;
    const float* h2cur = p ? h2b1 : h2b0;
    float*       h2nxt = p ? h2b0 : h2b1;

    // ---------------- layer 0 ----------------
    STAGE(h0cur);
    __syncthreads();
    float aR[4] = {0,0,0,0}, aZ[4] = {0,0,0,0}, aN[4] = {0,0,0,0};
    GEMM3(0, aR, aZ, aN);
    float hr = SEL4(KRED(aR[0]),KRED(aR[1]),KRED(aR[2]),KRED(aR[3])) + bh0g[0];
    float hz = SEL4(KRED(aZ[0]),KRED(aZ[1]),KRED(aZ[2]),KRED(aZ[3])) + bh0g[1];
    float hn = SEL4(KRED(aN[0]),KRED(aN[1]),KRED(aN[2]),KRED(aN[3])) + bh0g[2];
    float xr = bi0g[0], xz = bi0g[1], xn = bi0g[2];
    if (t < T_IN){
      const float* xp = x + (((bt << 4) + bi)*T_IN + t)*10;
      #pragma unroll
      for (int d = 0; d < 10; d++){
        float xv = xp[d];
        xr = fmaf(wi0[0][d], xv, xr);
        xz = fmaf(wi0[1][d], xv, xz);
        xn = fmaf(wi0[2][d], xv, xn);
      }
    }
    float r = sigf(xr + hr);
    float z = sigf(xz + hz);
    float n = tanhfast(xn + r*hn);
    float hold = Hl[((rowg >> 2) << 6) + (bi << 2) + (rowg & 3)];
    float hnew = fmaf(z, hold - n, n);            // (1-z)*n + z*h
    h0nxt[rowg*256 + (bt << 4) + bi] = hnew;

    // ---- barrier A: arrive (release) + wait; counter target = 32t+16 ----
    __syncthreads();
    if (tid == 0){
      __hip_atomic_fetch_add(mycnt, 1u, __ATOMIC_RELEASE, __HIP_MEMORY_SCOPE_AGENT);
      unsigned tgt = 32u*(unsigned)t + 16u;
      while (__hip_atomic_load(mycnt, __ATOMIC_ACQUIRE, __HIP_MEMORY_SCOPE_AGENT) < tgt){
        __builtin_amdgcn_s_sleep(2);
      }
    }
    __syncthreads();

    // ---------------- layer 1 ----------------
    STAGE(h0nxt);                      // h1[t] tile
    __syncthreads();
    float xR[4] = {0,0,0,0}, xZ[4] = {0,0,0,0}, xN[4] = {0,0,0,0};
    GEMM3(1, xR, xZ, xN);
    __syncthreads();
    STAGE(h2cur);
    __syncthreads();
    float bR[4] = {0,0,0,0}, bZ[4] = {0,0,0,0}, bN[4] = {0,0,0,0};
    GEMM3(2, bR, bZ, bN);
    float xr1 = SEL4(KRED(xR[0]),KRED(xR[1]),KRED(xR[2]),KRED(xR[3])) + bi1g[0];
    float xz1 = SEL4(KRED(xZ[0]),KRED(xZ[1]),KRED(xZ[2]),KRED(xZ[3])) + bi1g[1];
    float xn1 = SEL4(KRED(xN[0]),KRED(xN[1]),KRED(xN[2]),KRED(xN[3])) + bi1g[2];
    float hr1 = SEL4(KRED(bR[0]),KRED(bR[1]),KRED(bR[2]),KRED(bR[3])) + bh1g[0];
    float hz1 = SEL4(KRED(bZ[0]),KRED(bZ[1]),KRED(bZ[2]),KRED(bZ[3])) + bh1g[1];
    float hn1 = SEL4(KRED(bN[0]),KRED(bN[1]),KRED(bN[2]),KRED(bN[3])) + bh1g[2];
    float r1 = sigf(xr1 + hr1);
    float z1 = sigf(xz1 + hz1);
    float n1 = tanhfast(xn1 + r1*hn1);
    float h2old = Hl[((rowg >> 2) << 6) + (bi << 2) + (rowg & 3)];
    float h2new = fmaf(z1, h2old - n1, n1);
    h2nxt[rowg*256 + (bt << 4) + bi] = h2new;

    // projection: out[b][t-144] += sum_h h2[h][b]*wproj[h]
    if (t >= T_IN){
      float pp = h2new * wp;
      pp += __shfl_xor(pp, 16, 64);
      pp += __shfl_xor(pp, 32, 64);
      if ((tid & 63) < 16){
        atomicAdd(out + ((bt << 4) + (tid & 15))*T_OUT + (t - T_IN), pp);
      }
    }

    // ---- barrier B: arrive only (release); next step's A-wait covers it ----
    __syncthreads();
    if (tid == 0){
      __hip_atomic_fetch_add(mycnt, 1u, __ATOMIC_RELEASE, __HIP_MEMORY_SCOPE_AGENT);
    }
    p ^= 1;
  }
}

extern "C" void kernel_launch(void* const* d_in, const int* in_sizes, int n_in,
                              void* d_out, int out_size, void* d_ws, size_t ws_size,
                              hipStream_t stream){
  const float* x     = (const float*)d_in[0];
  const float* wih0  = (const float*)d_in[1];
  const float* whh0  = (const float*)d_in[2];
  const float* bih0  = (const float*)d_in[3];
  const float* bhh0  = (const float*)d_in[4];
  const float* wih1  = (const float*)d_in[5];
  const float* whh1  = (const float*)d_in[6];
  const float* bih1  = (const float*)d_in[7];
  const float* bhh1  = (const float*)d_in[8];
  const float* wproj = (const float*)d_in[9];
  const float* bproj = (const float*)d_in[10];
  float* out = (float*)d_out;
  float* ws  = (float*)d_ws;

  hipLaunchKernelGGL(gru_init, dim3(1024), dim3(THREADS), 0, stream, ws, out, bproj);

  hipFuncSetAttribute(reinterpret_cast<const void*>(gru_persist),
                      hipFuncAttributeMaxDynamicSharedMemorySize, 163840);

  void* args[] = {
    (void*)&x, (void*)&wih0, (void*)&whh0, (void*)&bih0, (void*)&bhh0,
    (void*)&wih1, (void*)&whh1, (void*)&bih1, (void*)&bhh1,
    (void*)&wproj, (void*)&out, (void*)&ws
  };
  hipLaunchCooperativeKernel(reinterpret_cast<void*>(gru_persist),
                             dim3(256), dim3(THREADS), args, 163840, stream);
}